// Round 7
// baseline (373.277 us; speedup 1.0000x reference)
//
#include <hip/hip_runtime.h>

#define B_SZ 16
#define L_SZ 1024
#define D_SZ 256
#define KW   16

typedef float f32x4 __attribute__((ext_vector_type(4)));
typedef short bf16x8 __attribute__((ext_vector_type(8)));
typedef unsigned int u32x4 __attribute__((ext_vector_type(4)));
typedef unsigned int u32x2 __attribute__((ext_vector_type(2)));

__device__ __forceinline__ float bf2f(unsigned short u) {
    union { unsigned int i; float f; } v; v.i = ((unsigned int)u) << 16; return v.f;
}
__device__ __forceinline__ unsigned short f2bf(float f) {
    union { float f; unsigned int i; } v; v.f = f;
    unsigned int r = v.i + 0x7fffu + ((v.i >> 16) & 1u);
    return (unsigned short)(r >> 16);
}
__device__ __forceinline__ float fast_sigmoid(float x) {
    float e = __builtin_amdgcn_exp2f(-1.44269504f * x);
    return __builtin_amdgcn_rcpf(1.0f + e);
}
__device__ __forceinline__ float fast_tanh(float x) {
    float e = __builtin_amdgcn_exp2f(-2.88539008f * x);
    return (1.0f - e) * __builtin_amdgcn_rcpf(1.0f + e);
}
__device__ __forceinline__ f32x4 zero4() { f32x4 v; v[0]=0.f; v[1]=0.f; v[2]=0.f; v[3]=0.f; return v; }

// ---------------------------------------------------------------------------
// prep: repack W_ih / W_hh into per-16-dim-slice contiguous bf16 streams:
// slice s=0..15 covers dims s*16..s*16+15; within slice: 3 gates x 8 ks x
// 512 shorts; lane l holds W[g*256+s*16+(l&15)][ks*32+(l>>4)*8+j].
// ---------------------------------------------------------------------------
__global__ void prep_kernel(const float* __restrict__ wih,
                            const float* __restrict__ whh,
                            unsigned short* __restrict__ wpkih,
                            unsigned short* __restrict__ wpkhh) {
    const int NW = 768 * 256;  // 196608
    for (int i = blockIdx.x * blockDim.x + threadIdx.x; i < 2 * NW;
         i += gridDim.x * blockDim.x) {
        const float* W = (i < NW) ? wih : whh;
        unsigned short* dst = (i < NW) ? wpkih : wpkhh;
        int t = (i < NW) ? i : (i - NW);
        int j = t & 7;
        int q = t >> 3;
        int colg = q & 15; q >>= 4;
        int kg = q & 3;    q >>= 2;
        int ks = q & 7;    q >>= 3;
        int g = q % 3;
        int s = q / 3;
        int src = (g * 256 + s * 16 + colg) * 256 + ks * 32 + kg * 8 + j;
        dst[t] = f2bf(W[src]);
    }
}

// ---------------------------------------------------------------------------
// v7: 256 blocks x 512 threads (8 waves) -- the (512,2) config that is
// PROVEN to get 128 VGPRs (R2), avoiding the 64-VGPR spill wall at 1024 thr.
// Phase 1: stage x window (80 rows bf16, swizzled)      -> xw  (40KB)
// Phase 2: one-time gi GEMM (+b_ih) -> gi LDS bf16 [79][768]  (118.5KB)
// Phase 3: 16-step recurrence; each step = TWO half-passes (dims 0-127,
//          128-255) reusing one acc set (48 VGPRs); h carried as bf16 in
//          single LDS buffer (aliases dead xw); hnew deferred in registers
//          across the read/write barrier; k=15 writes out in fp32 directly.
// ---------------------------------------------------------------------------
#define GI_PITCH 1536
#define XW_BASE  121344             /* 79*1536 */
#define LDS_BYTES (121344 + 80*512) /* 162304 */

__global__ __launch_bounds__(512, 2) void rnn_v7(
    const float* __restrict__ x,               // [B][L][256] fp32
    const unsigned short* __restrict__ wpkih,  // packed bf16
    const unsigned short* __restrict__ wpkhh,  // packed bf16
    const float* __restrict__ bih,             // [768]
    const float* __restrict__ bhh,             // [768]
    float* __restrict__ out) {                 // [B*L][256] fp32
    __shared__ u32x4 ldsv[LDS_BYTES / 16];
    char* lds = (char*)ldsv;
    char* gi = lds;                 // [79][1536B] swizzled
    char* xw = lds + XW_BASE;       // [80][512B]  swizzled
    char* hb = lds + XW_BASE;       // alias: [64][512B] swizzled (after xw dead)

    const int tid = threadIdx.x;
    const int wid = tid >> 6, lane = tid & 63;
    const int b = blockIdx.x >> 4;
    const int l0 = (blockIdx.x & 15) << 6;
    const int colg = lane & 15;
    const int kg = (lane >> 4) & 3;

    // ---- phase 1: stage x window (rows l0-15 .. l0+63) ----
    for (int c = tid; c < 5120; c += 512) {
        int row = c >> 6;                 // 0..79
        int f0 = (c & 63) * 4;
        int gl = l0 - (KW - 1) + row;
        u32x2 pk;
        if (gl >= 0 && gl < L_SZ) {
            f32x4 v = *(const f32x4*)(x + ((size_t)(b * L_SZ + gl)) * 256 + f0);
            pk[0] = (unsigned int)f2bf(v[0]) | ((unsigned int)f2bf(v[1]) << 16);
            pk[1] = (unsigned int)f2bf(v[2]) | ((unsigned int)f2bf(v[3]) << 16);
        } else {
            pk[0] = 0u; pk[1] = 0u;
        }
        *(u32x2*)(xw + row * 512 + ((f0 * 2) ^ ((row & 7) << 4))) = pk;
    }
    __syncthreads();

    // ---- phase 2: one-time gi GEMM (includes b_ih), two dim-halves ----
#pragma unroll 1
    for (int hp = 0; hp < 2; hp++) {
        const unsigned short* wb = wpkih + (size_t)(hp * 8 + wid) * 12288;
        const int dc = hp * 128 + wid * 16 + colg;
        const float bi0 = bih[dc];
        const float bi1 = bih[256 + dc];
        const float bi2 = bih[512 + dc];
#pragma unroll 1
        for (int tile = 0; tile < 5; tile++) {
            f32x4 a0 = zero4(), a1 = zero4(), a2 = zero4();
#pragma unroll
            for (int ks = 0; ks < 8; ks++) {
                bf16x8 w0 = *(const bf16x8*)(wb + (0 * 8 + ks) * 512 + lane * 8);
                bf16x8 w1 = *(const bf16x8*)(wb + (1 * 8 + ks) * 512 + lane * 8);
                bf16x8 w2 = *(const bf16x8*)(wb + (2 * 8 + ks) * 512 + lane * 8);
                int row = tile * 16 + colg;
                bf16x8 a = *(const bf16x8*)(xw + row * 512 +
                                            ((ks * 64 + kg * 16) ^ ((row & 7) << 4)));
                a0 = __builtin_amdgcn_mfma_f32_16x16x32_bf16(a, w0, a0, 0, 0, 0);
                a1 = __builtin_amdgcn_mfma_f32_16x16x32_bf16(a, w1, a1, 0, 0, 0);
                a2 = __builtin_amdgcn_mfma_f32_16x16x32_bf16(a, w2, a2, 0, 0, 0);
            }
#pragma unroll
            for (int rr = 0; rr < 4; rr++) {
                int row = tile * 16 + kg * 4 + rr;
                if (row < 79) {
                    int sw = (row & 7) << 4;
                    char* gr = gi + row * GI_PITCH;
                    *(unsigned short*)(gr + ((dc * 2) ^ sw)) = f2bf(a0[rr] + bi0);
                    *(unsigned short*)(gr + ((512 + dc * 2) ^ sw)) = f2bf(a1[rr] + bi1);
                    *(unsigned short*)(gr + ((1024 + dc * 2) ^ sw)) = f2bf(a2[rr] + bi2);
                }
            }
        }
    }
    __syncthreads();

    // ---- phase 3: 16-step recurrence, 2 half-passes per step ----
#pragma unroll 1
    for (int k = 0; k < KW; k++) {
        unsigned int hnewpk[2][8];
#pragma unroll
        for (int hp = 0; hp < 2; hp++) {
            const int dc = hp * 128 + wid * 16 + colg;
            const float bz0 = bhh[dc];
            const float bz1 = bhh[256 + dc];
            const float bhn = bhh[512 + dc];

            f32x4 ar[4], az[4], an_[4];
#pragma unroll
            for (int mt = 0; mt < 4; mt++) {
                ar[mt] = zero4(); az[mt] = zero4(); an_[mt] = zero4();
            }

            if (k > 0) {
                const unsigned short* wb = wpkhh + (size_t)(hp * 8 + wid) * 12288;
#pragma unroll
                for (int ks = 0; ks < 8; ks++) {
                    bf16x8 w0 = *(const bf16x8*)(wb + (0 * 8 + ks) * 512 + lane * 8);
                    bf16x8 w1 = *(const bf16x8*)(wb + (1 * 8 + ks) * 512 + lane * 8);
                    bf16x8 w2 = *(const bf16x8*)(wb + (2 * 8 + ks) * 512 + lane * 8);
                    const int kcol = ks * 64 + kg * 16;
#pragma unroll
                    for (int mt = 0; mt < 4; mt++) {
                        int row = mt * 16 + colg;
                        bf16x8 a = *(const bf16x8*)(hb + row * 512 +
                                                    (kcol ^ ((row & 7) << 4)));
                        ar[mt]  = __builtin_amdgcn_mfma_f32_16x16x32_bf16(a, w0, ar[mt], 0, 0, 0);
                        az[mt]  = __builtin_amdgcn_mfma_f32_16x16x32_bf16(a, w1, az[mt], 0, 0, 0);
                        an_[mt] = __builtin_amdgcn_mfma_f32_16x16x32_bf16(a, w2, an_[mt], 0, 0, 0);
                    }
                }
            }

            // gate math for this half's 16 elements
#pragma unroll
            for (int mt = 0; mt < 4; mt++) {
#pragma unroll
                for (int rr = 0; rr < 4; rr++) {
                    int row = mt * 16 + kg * 4 + rr;
                    int xrow = k + row;
                    int sw = (xrow & 7) << 4;
                    const char* gr = gi + xrow * GI_PITCH;
                    float ir  = bf2f(*(const unsigned short*)(gr + ((dc * 2) ^ sw)));
                    float iz  = bf2f(*(const unsigned short*)(gr + ((512 + dc * 2) ^ sw)));
                    float in_ = bf2f(*(const unsigned short*)(gr + ((1024 + dc * 2) ^ sw)));
                    float hold = (k > 0)
                        ? bf2f(*(const unsigned short*)(hb + row * 512 +
                                                        ((dc * 2) ^ ((row & 7) << 4))))
                        : 0.0f;
                    float r = fast_sigmoid(ir + ar[mt][rr] + bz0);
                    float z = fast_sigmoid(iz + az[mt][rr] + bz1);
                    float n = fast_tanh(in_ + r * (an_[mt][rr] + bhn));
                    float hnew = n + z * (hold - n);
                    if (k == KW - 1) {
                        out[((size_t)(b * L_SZ + l0 + row)) * D_SZ + dc] = hnew;
                    } else {
                        int e = mt * 4 + rr;
                        unsigned int bfv = f2bf(hnew);
                        if (e & 1) hnewpk[hp][e >> 1] |= bfv << 16;
                        else       hnewpk[hp][e >> 1]  = bfv;
                    }
                }
            }
        }

        if (k < KW - 1) {
            __syncthreads();  // all hb reads (GEMM + hold) done block-wide
#pragma unroll
            for (int hp = 0; hp < 2; hp++) {
                const int dc = hp * 128 + wid * 16 + colg;
#pragma unroll
                for (int mt = 0; mt < 4; mt++) {
#pragma unroll
                    for (int rr = 0; rr < 4; rr++) {
                        int row = mt * 16 + kg * 4 + rr;
                        int e = mt * 4 + rr;
                        unsigned int w = hnewpk[hp][e >> 1];
                        unsigned short hv = (e & 1) ? (unsigned short)(w >> 16)
                                                    : (unsigned short)(w & 0xffff);
                        *(unsigned short*)(hb + row * 512 +
                                           ((dc * 2) ^ ((row & 7) << 4))) = hv;
                    }
                }
            }
            __syncthreads();  // writes visible before next step's reads
        }
    }
}

// ---------------------------------------------------------------------------
extern "C" void kernel_launch(void* const* d_in, const int* in_sizes, int n_in,
                              void* d_out, int out_size, void* d_ws, size_t ws_size,
                              hipStream_t stream) {
    const float* x   = (const float*)d_in[0];
    const float* wih = (const float*)d_in[1];
    const float* whh = (const float*)d_in[2];
    const float* bih = (const float*)d_in[3];
    const float* bhh = (const float*)d_in[4];
    float* out = (float*)d_out;

    char* ws = (char*)d_ws;
    unsigned short* wpkih = (unsigned short*)(ws);           // 393,216 B
    unsigned short* wpkhh = (unsigned short*)(ws + 393216);  // 393,216 B

    prep_kernel<<<512, 256, 0, stream>>>(wih, whh, wpkih, wpkhh);
    rnn_v7<<<256, 512, 0, stream>>>(x, wpkih, wpkhh, bih, bhh, out);
}

// Round 10
// 292.770 us; speedup vs baseline: 1.2750x; 1.2750x over previous
//
#include <hip/hip_runtime.h>

#define B_SZ 16
#define L_SZ 1024
#define D_SZ 256
#define KW   16

typedef float f32x4 __attribute__((ext_vector_type(4)));
typedef short bf16x8 __attribute__((ext_vector_type(8)));
typedef unsigned int u32x4 __attribute__((ext_vector_type(4)));
typedef unsigned int u32x2 __attribute__((ext_vector_type(2)));
typedef unsigned short u16x4 __attribute__((ext_vector_type(4)));

__device__ __forceinline__ float bf2f(unsigned short u) {
    union { unsigned int i; float f; } v; v.i = ((unsigned int)u) << 16; return v.f;
}
__device__ __forceinline__ unsigned short f2bf(float f) {
    union { float f; unsigned int i; } v; v.f = f;
    unsigned int r = v.i + 0x7fffu + ((v.i >> 16) & 1u);
    return (unsigned short)(r >> 16);
}
__device__ __forceinline__ float fast_sigmoid(float x) {
    float e = __builtin_amdgcn_exp2f(-1.44269504f * x);
    return __builtin_amdgcn_rcpf(1.0f + e);
}
__device__ __forceinline__ float fast_tanh(float x) {
    float e = __builtin_amdgcn_exp2f(-2.88539008f * x);
    return (1.0f - e) * __builtin_amdgcn_rcpf(1.0f + e);
}
__device__ __forceinline__ f32x4 zero4() { f32x4 v; v[0]=0.f; v[1]=0.f; v[2]=0.f; v[3]=0.f; return v; }

// ---------------------------------------------------------------------------
// prep: repack W_ih / W_hh into per-16-dim-slice contiguous bf16 streams:
// slice s=0..15 covers dims s*16..s*16+15; within slice: 3 gates x 8 ks x
// 512 shorts; lane l holds W[g*256+s*16+(l&15)][ks*32+(l>>4)*8+j].
// ---------------------------------------------------------------------------
__global__ void prep_kernel(const float* __restrict__ wih,
                            const float* __restrict__ whh,
                            unsigned short* __restrict__ wpkih,
                            unsigned short* __restrict__ wpkhh) {
    const int NW = 768 * 256;  // 196608
    for (int i = blockIdx.x * blockDim.x + threadIdx.x; i < 2 * NW;
         i += gridDim.x * blockDim.x) {
        const float* W = (i < NW) ? wih : whh;
        unsigned short* dst = (i < NW) ? wpkih : wpkhh;
        int t = (i < NW) ? i : (i - NW);
        int j = t & 7;
        int q = t >> 3;
        int colg = q & 15; q >>= 4;
        int kg = q & 3;    q >>= 2;
        int ks = q & 7;    q >>= 3;
        int g = q % 3;
        int s = q / 3;
        int src = (g * 256 + s * 16 + colg) * 256 + ks * 32 + kg * 8 + j;
        dst[t] = f2bf(W[src]);
    }
}

// ---------------------------------------------------------------------------
// v8: 256 blocks x 512 threads (8 waves, 128 VGPR proven config).
// gi stored TRANSPOSED in LDS: gi_t[gate][dim][xrow(pad 80)] bf16, so all
// recurrence-phase gi accesses are base+imm ds_read_u16 (zero addr VALU),
// and phase-2 writes are ds_write_b64. xw (79 rows) overlaid by hb after
// phase 2. 2 half-passes per step reuse one 48-reg accumulator set; h kept
// bf16 in LDS; hnew deferred in packed regs across the RAW barrier.
// ---------------------------------------------------------------------------
#define GI_G_STRIDE 40960           /* 256*80*2 */
#define GI_D_STRIDE 160             /* 80*2 */
#define XW_BASE     122880          /* 3*40960 */
#define LDS_BYTES   (122880 + 79*512) /* 163328 <= 163840 */

__global__ __launch_bounds__(512, 2) void rnn_v8(
    const float* __restrict__ x,               // [B][L][256] fp32
    const unsigned short* __restrict__ wpkih,  // packed bf16
    const unsigned short* __restrict__ wpkhh,  // packed bf16
    const float* __restrict__ bih,             // [768]
    const float* __restrict__ bhh,             // [768]
    float* __restrict__ out) {                 // [B*L][256] fp32
    __shared__ u32x4 ldsv[LDS_BYTES / 16];
    char* lds = (char*)ldsv;
    char* gi = lds;                 // [3][256][80] bf16 transposed
    char* xw = lds + XW_BASE;       // [79][512B] swizzled
    char* hb = lds + XW_BASE;       // alias: [64][512B] swizzled

    const int tid = threadIdx.x;
    const int wid = tid >> 6, lane = tid & 63;
    const int b = blockIdx.x >> 4;
    const int l0 = (blockIdx.x & 15) << 6;
    const int colg = lane & 15;
    const int kg = (lane >> 4) & 3;

    // ---- phase 1: stage x window rows 0..78 (l0-15 .. l0+63) ----
    for (int c = tid; c < 5056; c += 512) {
        int row = c >> 6;                 // 0..78
        int f0 = (c & 63) * 4;
        int gl = l0 - (KW - 1) + row;
        u32x2 pk;
        if (gl >= 0 && gl < L_SZ) {
            f32x4 v = *(const f32x4*)(x + ((size_t)(b * L_SZ + gl)) * 256 + f0);
            pk[0] = (unsigned int)f2bf(v[0]) | ((unsigned int)f2bf(v[1]) << 16);
            pk[1] = (unsigned int)f2bf(v[2]) | ((unsigned int)f2bf(v[3]) << 16);
        } else {
            pk[0] = 0u; pk[1] = 0u;
        }
        *(u32x2*)(xw + row * 512 + ((f0 * 2) ^ ((row & 7) << 4))) = pk;
    }
    __syncthreads();

    // ---- phase 2: one-time gi GEMM (+b_ih) -> gi_t, two dim-halves ----
#pragma unroll 1
    for (int hp = 0; hp < 2; hp++) {
        const unsigned short* wb = wpkih + (size_t)(hp * 8 + wid) * 12288;
        const int dc = hp * 128 + wid * 16 + colg;
        const float bi0 = bih[dc];
        const float bi1 = bih[256 + dc];
        const float bi2 = bih[512 + dc];
        char* gcol = gi + dc * GI_D_STRIDE + kg * 8;  // +g*GI_G_STRIDE +tile*32
#pragma unroll 1
        for (int tile = 0; tile < 5; tile++) {
            f32x4 a0 = zero4(), a1 = zero4(), a2 = zero4();
#pragma unroll
            for (int ks = 0; ks < 8; ks++) {
                bf16x8 w0 = *(const bf16x8*)(wb + (0 * 8 + ks) * 512 + lane * 8);
                bf16x8 w1 = *(const bf16x8*)(wb + (1 * 8 + ks) * 512 + lane * 8);
                bf16x8 w2 = *(const bf16x8*)(wb + (2 * 8 + ks) * 512 + lane * 8);
                int row = tile * 16 + colg;
                if (row > 78) row = 78;   // C-row 79 discarded into pad
                bf16x8 a = *(const bf16x8*)(xw + row * 512 +
                                            ((ks * 64 + kg * 16) ^ ((row & 7) << 4)));
                a0 = __builtin_amdgcn_mfma_f32_16x16x32_bf16(a, w0, a0, 0, 0, 0);
                a1 = __builtin_amdgcn_mfma_f32_16x16x32_bf16(a, w1, a1, 0, 0, 0);
                a2 = __builtin_amdgcn_mfma_f32_16x16x32_bf16(a, w2, a2, 0, 0, 0);
            }
            u16x4 p0, p1, p2;
#pragma unroll
            for (int rr = 0; rr < 4; rr++) {
                p0[rr] = f2bf(a0[rr] + bi0);
                p1[rr] = f2bf(a1[rr] + bi1);
                p2[rr] = f2bf(a2[rr] + bi2);
            }
            // rows tile*16+kg*4 .. +3 (row 79 = pad, never read)
            *(u16x4*)(gcol + 0 * GI_G_STRIDE + tile * 32) = p0;
            *(u16x4*)(gcol + 1 * GI_G_STRIDE + tile * 32) = p1;
            *(u16x4*)(gcol + 2 * GI_G_STRIDE + tile * 32) = p2;
        }
    }
    __syncthreads();

    // ---- phase 3: 16-step recurrence, 2 half-passes per step ----
    // bias hoist (loop-invariant): [hp][gate]
    float bz0h[2], bz1h[2], bhnh[2];
#pragma unroll
    for (int hp = 0; hp < 2; hp++) {
        const int dc = hp * 128 + wid * 16 + colg;
        bz0h[hp] = bhh[dc];
        bz1h[hp] = bhh[256 + dc];
        bhnh[hp] = bhh[512 + dc];
    }

#pragma unroll 1
    for (int k = 0; k < KW; k++) {
        unsigned int hnewpk[2][8];
#pragma unroll
        for (int hp = 0; hp < 2; hp++) {
            const int dc = hp * 128 + wid * 16 + colg;
            const float bz0 = bz0h[hp];
            const float bz1 = bz1h[hp];
            const float bhn = bhnh[hp];
            // gi column base for this (hp,k): all accesses base+imm
            const unsigned short* gp =
                (const unsigned short*)(gi + dc * GI_D_STRIDE + kg * 8 + k * 2);
            // h column base (swizzled writes/reads share addressing)
            const int hcol2 = dc * 2;

            f32x4 ar[4], az[4], an_[4];
#pragma unroll
            for (int mt = 0; mt < 4; mt++) {
                ar[mt] = zero4(); az[mt] = zero4(); an_[mt] = zero4();
            }

            if (k > 0) {
                const unsigned short* wb = wpkhh + (size_t)(hp * 8 + wid) * 12288;
#pragma unroll
                for (int ks = 0; ks < 8; ks++) {
                    bf16x8 w0 = *(const bf16x8*)(wb + (0 * 8 + ks) * 512 + lane * 8);
                    bf16x8 w1 = *(const bf16x8*)(wb + (1 * 8 + ks) * 512 + lane * 8);
                    bf16x8 w2 = *(const bf16x8*)(wb + (2 * 8 + ks) * 512 + lane * 8);
                    const int kcol = ks * 64 + kg * 16;
#pragma unroll
                    for (int mt = 0; mt < 4; mt++) {
                        int row = mt * 16 + colg;
                        bf16x8 a = *(const bf16x8*)(hb + row * 512 +
                                                    (kcol ^ ((row & 7) << 4)));
                        ar[mt]  = __builtin_amdgcn_mfma_f32_16x16x32_bf16(a, w0, ar[mt], 0, 0, 0);
                        az[mt]  = __builtin_amdgcn_mfma_f32_16x16x32_bf16(a, w1, az[mt], 0, 0, 0);
                        an_[mt] = __builtin_amdgcn_mfma_f32_16x16x32_bf16(a, w2, an_[mt], 0, 0, 0);
                    }
                }
            }

            // gate math; gi reads are base+imm u16 (no addr VALU)
#pragma unroll
            for (int mt = 0; mt < 4; mt++) {
#pragma unroll
                for (int rr = 0; rr < 4; rr++) {
                    const int ro = mt * 16 + rr;  // xrow offset from k (+kg*8 bytes in base)
                    float ir  = bf2f(gp[0 * (GI_G_STRIDE / 2) + ro]);
                    float iz  = bf2f(gp[1 * (GI_G_STRIDE / 2) + ro]);
                    float in_ = bf2f(gp[2 * (GI_G_STRIDE / 2) + ro]);
                    int row = mt * 16 + kg * 4 + rr;
                    float hold = (k > 0)
                        ? bf2f(*(const unsigned short*)(hb + row * 512 +
                                                        (hcol2 ^ ((row & 7) << 4))))
                        : 0.0f;
                    float r = fast_sigmoid(ir + ar[mt][rr] + bz0);
                    float z = fast_sigmoid(iz + az[mt][rr] + bz1);
                    float n = fast_tanh(in_ + r * (an_[mt][rr] + bhn));
                    float hnew = n + z * (hold - n);
                    if (k == KW - 1) {
                        out[((size_t)(b * L_SZ + l0 + row)) * D_SZ + dc] = hnew;
                    } else {
                        int e = mt * 4 + rr;
                        unsigned int bfv = f2bf(hnew);
                        if (e & 1) hnewpk[hp][e >> 1] |= bfv << 16;
                        else       hnewpk[hp][e >> 1]  = bfv;
                    }
                }
            }
        }

        if (k < KW - 1) {
            __syncthreads();  // all hb reads (GEMM + hold) done block-wide
#pragma unroll
            for (int hp = 0; hp < 2; hp++) {
                const int hcol2 = (hp * 128 + wid * 16 + colg) * 2;
#pragma unroll
                for (int mt = 0; mt < 4; mt++) {
#pragma unroll
                    for (int rr = 0; rr < 4; rr++) {
                        int row = mt * 16 + kg * 4 + rr;
                        int e = mt * 4 + rr;
                        unsigned int w = hnewpk[hp][e >> 1];
                        unsigned short hv = (e & 1) ? (unsigned short)(w >> 16)
                                                    : (unsigned short)(w & 0xffff);
                        *(unsigned short*)(hb + row * 512 +
                                           (hcol2 ^ ((row & 7) << 4))) = hv;
                    }
                }
            }
            __syncthreads();  // writes visible before next step's reads
        }
    }
}

// ---------------------------------------------------------------------------
extern "C" void kernel_launch(void* const* d_in, const int* in_sizes, int n_in,
                              void* d_out, int out_size, void* d_ws, size_t ws_size,
                              hipStream_t stream) {
    const float* x   = (const float*)d_in[0];
    const float* wih = (const float*)d_in[1];
    const float* whh = (const float*)d_in[2];
    const float* bih = (const float*)d_in[3];
    const float* bhh = (const float*)d_in[4];
    float* out = (float*)d_out;

    char* ws = (char*)d_ws;
    unsigned short* wpkih = (unsigned short*)(ws);           // 393,216 B
    unsigned short* wpkhh = (unsigned short*)(ws + 393216);  // 393,216 B

    prep_kernel<<<512, 256, 0, stream>>>(wih, whh, wpkih, wpkhh);
    rnn_v8<<<256, 512, 0, stream>>>(x, wpkih, wpkhh, bih, bhh, out);
}